// Round 1
// baseline (276.283 us; speedup 1.0000x reference)
//
#include <hip/hip_runtime.h>

#define LOG2E 1.4426950408889634f
#define NB 4
#define NL 256
#define ND 256
#define NH 256

typedef __attribute__((ext_vector_type(8))) short s16x8;
typedef __attribute__((ext_vector_type(4))) short s16x4;
typedef __attribute__((ext_vector_type(4))) float f32x4;

static __device__ __forceinline__ float b2f(unsigned short u) {
  return __builtin_bit_cast(float, (unsigned int)u << 16);
}
static __device__ __forceinline__ unsigned short f2b(float f) {
  unsigned int x = __builtin_bit_cast(unsigned int, f);
  return (unsigned short)((x + 0x7fffu + ((x >> 16) & 1u)) >> 16);
}
static __device__ __forceinline__ float ftanh(float x) {
  float e = __builtin_amdgcn_exp2f(x * 2.8853900817779268f);
  return 1.0f - 2.0f * __builtin_amdgcn_rcpf(e + 1.0f);
}

// ws layout (4.75 MB):
//   X    fp32 [0,      1M)  : Hq@Wb
//   C1   bf16 [1M,   1.5M)  : Hq@Wc1
//   M1   bf16 [1.5M,   2M)  : Hq@Wm
//   C2b  bf16 [2M,   2.5M)  : Hp@Wc2
//   M2b  bf16 [2.5M,   3M)  : Hp@Wm
//   Hqb  bf16 [3M,   3.5M)  : bf16(Hq)
//   SD   fp32 [3.5M, 4.5M)  : branch-d raw scores
//   WdT  fp32 [4.5M, 4.75M) : Wd transposed [h][k]

__global__ void __launch_bounds__(256) prep(
    const float* __restrict__ Hq, const float* __restrict__ Hp,
    const float* __restrict__ Wc1, const float* __restrict__ Wc2,
    const float* __restrict__ Wb, const float* __restrict__ Wm,
    const float* __restrict__ Wd, float* __restrict__ ws)
{
  const int which = blockIdx.y;  // 0=C1 1=M1 2=X 3=C2b 4=M2b 5=Hqb 6=WdT
  const int tid = threadIdx.x;
  if (which == 5) {
    const int m0 = blockIdx.x * 8;
    unsigned short* Hqb = (unsigned short*)((char*)ws + 3145728);
    #pragma unroll
    for (int j = 0; j < 8; ++j)
      Hqb[(m0 + j) * ND + tid] = f2b(Hq[(m0 + j) * ND + tid]);
    return;
  }
  __shared__ __align__(16) float a_s[8][256];
  if (which == 6) {
    if (blockIdx.x >= 32) return;
    const int k0 = blockIdx.x * 8;
    #pragma unroll
    for (int kk = 0; kk < 8; ++kk)
      a_s[kk][tid] = Wd[(k0 + kk) * NH + tid];
    __syncthreads();
    float* WdT = (float*)((char*)ws + 4718592);
    f32x4 v0 = {a_s[0][tid], a_s[1][tid], a_s[2][tid], a_s[3][tid]};
    f32x4 v1 = {a_s[4][tid], a_s[5][tid], a_s[6][tid], a_s[7][tid]};
    *(f32x4*)(WdT + tid * 256 + k0) = v0;
    *(f32x4*)(WdT + tid * 256 + k0 + 4) = v1;
    return;
  }
  const int m0 = blockIdx.x * 8;
  const float* A = (which >= 3) ? Hp : Hq;
  const float* W = (which == 0) ? Wc1 : (which == 1) ? Wm :
                   (which == 2) ? Wb  : (which == 3) ? Wc2 : Wm;
  #pragma unroll
  for (int j = 0; j < 8; ++j)
    a_s[j][tid] = A[(m0 + j) * ND + tid];
  __syncthreads();
  float acc[8] = {0.f, 0.f, 0.f, 0.f, 0.f, 0.f, 0.f, 0.f};
  for (int k = 0; k < 256; ++k) {
    const float w = W[k * NH + tid];
    #pragma unroll
    for (int j = 0; j < 8; ++j) acc[j] += a_s[j][k] * w;
  }
  if (which == 2) {
    #pragma unroll
    for (int j = 0; j < 8; ++j) ws[(m0 + j) * NH + tid] = acc[j];
  } else if (which < 2) {
    unsigned short* O = (unsigned short*)((char*)ws + 1048576 + which * 524288);
    #pragma unroll
    for (int j = 0; j < 8; ++j) O[(m0 + j) * NH + tid] = f2b(acc[j]);
  } else {
    unsigned short* O = (unsigned short*)((char*)ws + 2097152 + (which - 3) * 524288);
    #pragma unroll
    for (int j = 0; j < 8; ++j) O[(m0 + j) * NH + tid] = f2b(acc[j]);
  }
}

// ---- branch d: per (b,p) MFMA GEMM + tanh reduce -> SD
// 512 threads (8 waves x 32 q-rows), h-tile 32, WdT-vectorized staging.
__global__ void __launch_bounds__(512, 8) dkernel(
    const float* __restrict__ Hp, const float* __restrict__ vd,
    float* __restrict__ ws)
{
  const int p = blockIdx.x, b = blockIdx.y;
  const int tid = threadIdx.x;
  const int wave = tid >> 6, lane = tid & 63;
  const int quad = lane >> 4, c16 = lane & 15;

  __shared__ __align__(16) short Bs[32 * 264];  // [h][k], 16.9 KB
  __shared__ __align__(16) float hp_s[256];
  __shared__ __align__(16) float vd2_s[256];    // 2*vd

  const unsigned short* Hqb = (const unsigned short*)((const char*)ws + 3145728);
  const float* WdT = (const float*)((const char*)ws + 4718592);
  float* SD = (float*)((char*)ws + 3670016);

  if (tid < 256) {
    hp_s[tid] = Hp[(b * NL + p) * ND + tid];
    vd2_s[tid] = 2.0f * vd[tid];
  }
  __syncthreads();

  const int wq0 = wave * 32;
  const unsigned short* Aq = Hqb + (b * NL + wq0) * ND;

  // per-lane partials: sd = 0.5*vs2 - sdp  after 16-lane reduce
  float sdp[2][4];
  #pragma unroll
  for (int mt = 0; mt < 2; ++mt)
    #pragma unroll
    for (int r = 0; r < 4; ++r) sdp[mt][r] = 0.f;
  float vs2 = 0.f;

  const int k0s = (tid & 31) * 8;  // staging k-chunk
  const int hbs = tid >> 5;        // staging h base (0..15)

  for (int ht = 0; ht < 8; ++ht) {
    const int h0 = ht * 32;
    __syncthreads();
    { // stage Bs[h][k] = bf16(WdT[h0+h][k] * hp[k]), h in [0,32)
      f32x4 hpa = *(const f32x4*)(hp_s + k0s);
      f32x4 hpb = *(const f32x4*)(hp_s + k0s + 4);
      #pragma unroll
      for (int hi = 0; hi < 2; ++hi) {
        const int h = hbs + hi * 16;
        const float* wr = WdT + (h0 + h) * ND + k0s;
        f32x4 w0 = *(const f32x4*)(wr);
        f32x4 w1 = *(const f32x4*)(wr + 4);
        s16x8 bv;
        #pragma unroll
        for (int j = 0; j < 4; ++j) bv[j] = (short)f2b(w0[j] * hpa[j]);
        #pragma unroll
        for (int j = 0; j < 4; ++j) bv[4 + j] = (short)f2b(w1[j] * hpb[j]);
        *(s16x8*)(Bs + h * 264 + k0s) = bv;
      }
    }
    __syncthreads();

    f32x4 acc[2][2];
    #pragma unroll
    for (int mt = 0; mt < 2; ++mt)
      #pragma unroll
      for (int nt = 0; nt < 2; ++nt) acc[mt][nt] = f32x4{0.f, 0.f, 0.f, 0.f};

    #pragma unroll 2
    for (int kt = 0; kt < 8; ++kt) {
      const int k0 = kt * 32;
      s16x8 a8[2];
      #pragma unroll
      for (int mt = 0; mt < 2; ++mt)
        a8[mt] = *(const s16x8*)(Aq + (mt * 16 + c16) * ND + k0 + quad * 8);
      #pragma unroll
      for (int nt = 0; nt < 2; ++nt) {
        s16x8 b8 = *(const s16x8*)(Bs + (nt * 16 + c16) * 264 + k0 + quad * 8);
        #pragma unroll
        for (int mt = 0; mt < 2; ++mt)
          acc[mt][nt] = __builtin_amdgcn_mfma_f32_16x16x32_bf16(
              a8[mt], b8, acc[mt][nt], 0, 0, 0);
      }
    }

    // vd[h]*tanh(z) = vd[h] - vd2[h]*rcp(e^{2z}+1); accumulate the rcp part
    const float v2a = vd2_s[h0 + c16];
    const float v2b = vd2_s[h0 + 16 + c16];
    vs2 += v2a + v2b;
    #pragma unroll
    for (int mt = 0; mt < 2; ++mt) {
      #pragma unroll
      for (int r = 0; r < 4; ++r) {
        float e0 = __builtin_amdgcn_exp2f(acc[mt][0][r] * 2.8853900817779268f);
        sdp[mt][r] += v2a * __builtin_amdgcn_rcpf(e0 + 1.0f);
        float e1 = __builtin_amdgcn_exp2f(acc[mt][1][r] * 2.8853900817779268f);
        sdp[mt][r] += v2b * __builtin_amdgcn_rcpf(e1 + 1.0f);
      }
    }
  }

  // single deferred 16-lane reduce
  #pragma unroll
  for (int m = 1; m < 16; m <<= 1) vs2 += __shfl_xor(vs2, m, 64);
  #pragma unroll
  for (int mt = 0; mt < 2; ++mt)
    #pragma unroll
    for (int r = 0; r < 4; ++r) {
      float v = sdp[mt][r];
      #pragma unroll
      for (int m = 1; m < 16; m <<= 1) v += __shfl_xor(v, m, 64);
      if (c16 == 0)
        SD[(b * NL + p) * NL + wq0 + mt * 16 + quad * 4 + r] = 0.5f * vs2 - v;
    }
}

// ---- scores c/b/m + softmax(all 4) + attend(all 4)
__global__ void __launch_bounds__(256) fused2(
    const float* __restrict__ Hp, const float* __restrict__ Hq,
    const float* __restrict__ vc, const float* __restrict__ vm,
    const float* __restrict__ ws, float* __restrict__ out)
{
  const int p = blockIdx.x, b = blockIdx.y;
  const int tid = threadIdx.x;
  const int wave = tid >> 6, lane = tid & 63;
  const int c16 = lane & 15;

  __shared__ __align__(16) float sc4[4 * 256];  // rows: 0=c 1=b 2=d 3=m
  __shared__ __align__(16) float red[4][4][256]; // [wave][branch][d]
  __shared__ __align__(16) float hp_s[256];
  __shared__ __align__(16) float c2_s[256];
  __shared__ __align__(16) float m2_s[256];
  __shared__ __align__(16) float vc_s[256];
  __shared__ __align__(16) float vm_s[256];
  __shared__ __align__(16) float invsum[4];

  const float* X = ws;
  const unsigned short* C1  = (const unsigned short*)((const char*)ws + 1048576);
  const unsigned short* M1  = (const unsigned short*)((const char*)ws + 1572864);
  const unsigned short* C2b = (const unsigned short*)((const char*)ws + 2097152);
  const unsigned short* M2b = (const unsigned short*)((const char*)ws + 2621440);
  const float* SD = (const float*)((const char*)ws + 3670016);

  {
    const int r = (b * NL + p) * ND + tid;
    hp_s[tid] = Hp[r];
    c2_s[tid] = b2f(C2b[r]);
    m2_s[tid] = b2f(M2b[r]);
    vc_s[tid] = vc[tid];
    vm_s[tid] = vm[tid];
    sc4[512 + tid] = SD[(b * NL + p) * NL + tid];
  }
  __syncthreads();

  { // scores c, b, m
    const int qsub = lane >> 4;
    const int hb = c16 * 4;
    for (int qg = 0; qg < 16; ++qg) {
      const int q = wave * 64 + qg * 4 + qsub;
      const unsigned short* c1r = C1 + (b * NL + q) * NH;
      const unsigned short* m1r = M1 + (b * NL + q) * NH;
      const float* xr = X + (b * NL + q) * ND;
      float pc = 0.f, pm = 0.f, pb = 0.f;
      #pragma unroll
      for (int hi = 0; hi < 4; ++hi) {
        const int h = hb + hi * 64;
        s16x4 c1v = *(const s16x4*)(c1r + h);
        s16x4 m1v = *(const s16x4*)(m1r + h);
        f32x4 xv  = *(const f32x4*)(xr + h);
        #pragma unroll
        for (int i = 0; i < 4; ++i) {
          pc += vc_s[h + i] * ftanh(b2f((unsigned short)c1v[i]) + c2_s[h + i]);
          pm += vm_s[h + i] * ftanh(b2f((unsigned short)m1v[i]) - m2_s[h + i]);
          pb += hp_s[h + i] * xv[i];
        }
      }
      #pragma unroll
      for (int m = 1; m < 16; m <<= 1) {
        pc += __shfl_xor(pc, m, 64);
        pm += __shfl_xor(pm, m, 64);
        pb += __shfl_xor(pb, m, 64);
      }
      if (c16 == 0) {
        sc4[q]       = pc;
        sc4[256 + q] = pb;
        sc4[768 + q] = pm;
      }
    }
  }
  __syncthreads();

  { // softmax; wave w owns branch w (0=c,1=b,2=d,3=m)
    float s0 = sc4[wave * 256 + lane];
    float s1 = sc4[wave * 256 + lane + 64];
    float s2 = sc4[wave * 256 + lane + 128];
    float s3 = sc4[wave * 256 + lane + 192];
    float mx = fmaxf(fmaxf(s0, s1), fmaxf(s2, s3));
    #pragma unroll
    for (int m = 1; m < 64; m <<= 1) mx = fmaxf(mx, __shfl_xor(mx, m, 64));
    float e0 = __builtin_amdgcn_exp2f((s0 - mx) * LOG2E);
    float e1 = __builtin_amdgcn_exp2f((s1 - mx) * LOG2E);
    float e2 = __builtin_amdgcn_exp2f((s2 - mx) * LOG2E);
    float e3 = __builtin_amdgcn_exp2f((s3 - mx) * LOG2E);
    float sm = e0 + e1 + e2 + e3;
    #pragma unroll
    for (int m = 1; m < 64; m <<= 1) sm += __shfl_xor(sm, m, 64);
    sc4[wave * 256 + lane]       = e0;
    sc4[wave * 256 + lane + 64]  = e1;
    sc4[wave * 256 + lane + 128] = e2;
    sc4[wave * 256 + lane + 192] = e3;
    if (lane == 0) invsum[wave] = __builtin_amdgcn_rcpf(sm);
  }
  __syncthreads();

  { // attend: wave w covers q in [64w,64w+64) for ALL branches; Hq read once
    const int q0 = wave * 64;
    f32x4 pa0 = {0.f,0.f,0.f,0.f}, pa1 = {0.f,0.f,0.f,0.f};
    f32x4 pa2 = {0.f,0.f,0.f,0.f}, pa3 = {0.f,0.f,0.f,0.f};
    for (int qi = 0; qi < 64; ++qi) {
      const int q = q0 + qi;
      const float ac = sc4[q];
      const float ab = sc4[256 + q];
      const float ad = sc4[512 + q];
      const float am = sc4[768 + q];
      f32x4 hv = *(const f32x4*)(Hq + (b * NL + q) * ND + lane * 4);
      pa0 += ac * hv; pa1 += ab * hv; pa2 += ad * hv; pa3 += am * hv;
    }
    *(f32x4*)(&red[wave][0][lane * 4]) = pa0;
    *(f32x4*)(&red[wave][1][lane * 4]) = pa1;
    *(f32x4*)(&red[wave][2][lane * 4]) = pa2;
    *(f32x4*)(&red[wave][3][lane * 4]) = pa3;
  }
  __syncthreads();

  { // cross-wave reduce + normalize + store; thread owns d=tid for 4 branches
    #pragma unroll
    for (int br = 0; br < 4; ++br) {
      float s = red[0][br][tid] + red[1][br][tid] + red[2][br][tid] + red[3][br][tid];
      out[((br * NB + b) * NL + p) * ND + tid] = s * invsum[br];
    }
  }
}

extern "C" void kernel_launch(void* const* d_in, const int* in_sizes, int n_in,
                              void* d_out, int out_size, void* d_ws, size_t ws_size,
                              hipStream_t stream) {
  const float* Hp  = (const float*)d_in[0];
  const float* Hq  = (const float*)d_in[1];
  const float* Wc1 = (const float*)d_in[2];
  const float* Wc2 = (const float*)d_in[3];
  const float* vc  = (const float*)d_in[4];
  const float* Wb  = (const float*)d_in[5];
  const float* Wd  = (const float*)d_in[6];
  const float* vd  = (const float*)d_in[7];
  const float* Wm  = (const float*)d_in[8];
  const float* vm  = (const float*)d_in[9];
  float* ws = (float*)d_ws;
  float* out = (float*)d_out;

  hipLaunchKernelGGL(prep, dim3(128, 7), dim3(256), 0, stream,
                     Hq, Hp, Wc1, Wc2, Wb, Wm, Wd, ws);
  hipLaunchKernelGGL(dkernel, dim3(256, 4), dim3(512), 0, stream,
                     Hp, vd, ws);
  hipLaunchKernelGGL(fused2, dim3(256, 4), dim3(256), 0, stream,
                     Hp, Hq, vc, vm, ws, out);
}

// Round 2
// 263.729 us; speedup vs baseline: 1.0476x; 1.0476x over previous
//
#include <hip/hip_runtime.h>

#define LOG2E 1.4426950408889634f
#define NB 4
#define NL 256
#define ND 256
#define NH 256

typedef __attribute__((ext_vector_type(8))) short s16x8;
typedef __attribute__((ext_vector_type(4))) short s16x4;
typedef __attribute__((ext_vector_type(4))) float f32x4;

static __device__ __forceinline__ float b2f(unsigned short u) {
  return __builtin_bit_cast(float, (unsigned int)u << 16);
}
static __device__ __forceinline__ unsigned short f2b(float f) {
  unsigned int x = __builtin_bit_cast(unsigned int, f);
  return (unsigned short)((x + 0x7fffu + ((x >> 16) & 1u)) >> 16);
}
static __device__ __forceinline__ float ftanh(float x) {
  float e = __builtin_amdgcn_exp2f(x * 2.8853900817779268f);
  return 1.0f - 2.0f * __builtin_amdgcn_rcpf(e + 1.0f);
}

// ws layout (4.5 MB):
//   X    fp32 [0,      1M)  : Hq@Wb
//   C1   bf16 [1M,   1.5M)  : Hq@Wc1
//   M1   bf16 [1.5M,   2M)  : Hq@Wm
//   C2b  bf16 [2M,   2.5M)  : Hp@Wc2
//   M2b  bf16 [2.5M,   3M)  : Hp@Wm
//   Wdb  bf16 [3M,  3.125M) : Wd^T  [h][k]  (128 KB)
//   SD   fp32 [3.5M, 4.5M)  : branch-d raw scores

__global__ void __launch_bounds__(256) prep(
    const float* __restrict__ Hq, const float* __restrict__ Hp,
    const float* __restrict__ Wc1, const float* __restrict__ Wc2,
    const float* __restrict__ Wb, const float* __restrict__ Wm,
    const float* __restrict__ Wd, float* __restrict__ ws)
{
  const int which = blockIdx.y;  // 0=C1 1=M1 2=X 3=C2b 4=M2b 5=Wdb
  const int tid = threadIdx.x;
  __shared__ __align__(16) float a_s[8][256];
  if (which == 5) {
    // transpose Wd -> Wdb[h][k] bf16 via LDS
    if (blockIdx.x >= 32) return;
    const int k0 = blockIdx.x * 8;
    #pragma unroll
    for (int kk = 0; kk < 8; ++kk)
      a_s[kk][tid] = Wd[(k0 + kk) * NH + tid];
    __syncthreads();
    unsigned short* Wdb = (unsigned short*)((char*)ws + 3145728);
    s16x8 v;
    #pragma unroll
    for (int kk = 0; kk < 8; ++kk) v[kk] = (short)f2b(a_s[kk][tid]);
    *(s16x8*)(Wdb + tid * 256 + k0) = v;
    return;
  }
  const int m0 = blockIdx.x * 8;
  const float* A = (which >= 3) ? Hp : Hq;
  const float* W = (which == 0) ? Wc1 : (which == 1) ? Wm :
                   (which == 2) ? Wb  : (which == 3) ? Wc2 : Wm;
  #pragma unroll
  for (int j = 0; j < 8; ++j)
    a_s[j][tid] = A[(m0 + j) * ND + tid];
  __syncthreads();
  float acc[8] = {0.f, 0.f, 0.f, 0.f, 0.f, 0.f, 0.f, 0.f};
  for (int k = 0; k < 256; ++k) {
    const float w = W[k * NH + tid];
    #pragma unroll
    for (int j = 0; j < 8; ++j) acc[j] += a_s[j][k] * w;
  }
  if (which == 2) {
    #pragma unroll
    for (int j = 0; j < 8; ++j) ws[(m0 + j) * NH + tid] = acc[j];
  } else if (which < 2) {
    unsigned short* O = (unsigned short*)((char*)ws + 1048576 + which * 524288);
    #pragma unroll
    for (int j = 0; j < 8; ++j) O[(m0 + j) * NH + tid] = f2b(acc[j]);
  } else {
    unsigned short* O = (unsigned short*)((char*)ws + 2097152 + (which - 3) * 524288);
    #pragma unroll
    for (int j = 0; j < 8; ++j) O[(m0 + j) * NH + tid] = f2b(acc[j]);
  }
}

// ---- branch d: per (b,p). A' = bf16(Hq*hp) cached in regs; B = Wdb (global,
// L1/L2-hot, shared by ALL blocks). No LDS staging, no barriers in main loop.
__global__ void __launch_bounds__(256, 2) dkernel(
    const float* __restrict__ Hq, const float* __restrict__ Hp,
    const float* __restrict__ vd, float* __restrict__ ws)
{
  const int p = blockIdx.x, b = blockIdx.y;
  const int tid = threadIdx.x;
  const int wave = tid >> 6, lane = tid & 63;
  const int quad = lane >> 4, c16 = lane & 15;

  __shared__ __align__(16) float hp_s[256];
  __shared__ __align__(16) float vd2_s[256];  // 2*vd

  const unsigned short* Wdb = (const unsigned short*)((const char*)ws + 3145728);
  float* SD = (float*)((char*)ws + 3670016);

  hp_s[tid] = Hp[(b * NL + p) * ND + tid];
  vd2_s[tid] = 2.0f * vd[tid];
  __syncthreads();

  const int wq0 = wave * 64;

  // build A fragments once: a[mt][kt], row = wq0+mt*16+c16, k = kt*32+quad*8..+8
  s16x8 a[4][8];
  #pragma unroll
  for (int kt = 0; kt < 8; ++kt) {
    const int k0 = kt * 32 + quad * 8;
    f32x4 hp0 = *(const f32x4*)(hp_s + k0);
    f32x4 hp1 = *(const f32x4*)(hp_s + k0 + 4);
    #pragma unroll
    for (int mt = 0; mt < 4; ++mt) {
      const float* hq = Hq + (b * NL + wq0 + mt * 16 + c16) * ND + k0;
      f32x4 q0 = *(const f32x4*)(hq);
      f32x4 q1 = *(const f32x4*)(hq + 4);
      s16x8 av;
      #pragma unroll
      for (int j = 0; j < 4; ++j) av[j] = (short)f2b(q0[j] * hp0[j]);
      #pragma unroll
      for (int j = 0; j < 4; ++j) av[4 + j] = (short)f2b(q1[j] * hp1[j]);
      a[mt][kt] = av;
    }
  }

  // sd = 0.5*vs2 - sdp after 16-lane reduce
  float sdp[4][4];
  #pragma unroll
  for (int mt = 0; mt < 4; ++mt)
    #pragma unroll
    for (int r = 0; r < 4; ++r) sdp[mt][r] = 0.f;
  float vs2 = 0.f;

  for (int ht = 0; ht < 4; ++ht) {
    const int h0 = ht * 64;

    f32x4 acc[4][4];
    #pragma unroll
    for (int mt = 0; mt < 4; ++mt)
      #pragma unroll
      for (int nt = 0; nt < 4; ++nt) acc[mt][nt] = f32x4{0.f, 0.f, 0.f, 0.f};

    #pragma unroll
    for (int kt = 0; kt < 8; ++kt) {
      const int k0 = kt * 32 + quad * 8;
      #pragma unroll
      for (int nt = 0; nt < 4; ++nt) {
        s16x8 b8 = *(const s16x8*)(Wdb + (h0 + nt * 16 + c16) * 256 + k0);
        #pragma unroll
        for (int mt = 0; mt < 4; ++mt)
          acc[mt][nt] = __builtin_amdgcn_mfma_f32_16x16x32_bf16(
              a[mt][kt], b8, acc[mt][nt], 0, 0, 0);
      }
    }

    // vd[h]*tanh(z) = vd[h] - vd2[h]*rcp(e^{2z}+1)
    #pragma unroll
    for (int nt = 0; nt < 4; ++nt) {
      const float v2 = vd2_s[h0 + nt * 16 + c16];
      vs2 += v2;
      #pragma unroll
      for (int mt = 0; mt < 4; ++mt) {
        #pragma unroll
        for (int r = 0; r < 4; ++r) {
          float e = __builtin_amdgcn_exp2f(acc[mt][nt][r] * 2.8853900817779268f);
          sdp[mt][r] += v2 * __builtin_amdgcn_rcpf(e + 1.0f);
        }
      }
    }
  }

  // single deferred 16-lane reduce
  #pragma unroll
  for (int m = 1; m < 16; m <<= 1) vs2 += __shfl_xor(vs2, m, 64);
  #pragma unroll
  for (int mt = 0; mt < 4; ++mt)
    #pragma unroll
    for (int r = 0; r < 4; ++r) {
      float v = sdp[mt][r];
      #pragma unroll
      for (int m = 1; m < 16; m <<= 1) v += __shfl_xor(v, m, 64);
      if (c16 == 0)
        SD[(b * NL + p) * NL + wq0 + mt * 16 + quad * 4 + r] = 0.5f * vs2 - v;
    }
}

// ---- scores c/b/m + softmax(all 4) + attend(all 4)
__global__ void __launch_bounds__(256) fused2(
    const float* __restrict__ Hp, const float* __restrict__ Hq,
    const float* __restrict__ vc, const float* __restrict__ vm,
    const float* __restrict__ ws, float* __restrict__ out)
{
  const int p = blockIdx.x, b = blockIdx.y;
  const int tid = threadIdx.x;
  const int wave = tid >> 6, lane = tid & 63;
  const int c16 = lane & 15;

  __shared__ __align__(16) float sc4[4 * 256];  // rows: 0=c 1=b 2=d 3=m
  __shared__ __align__(16) float red[4][4][256]; // [wave][branch][d]
  __shared__ __align__(16) float hp_s[256];
  __shared__ __align__(16) float c2_s[256];
  __shared__ __align__(16) float m2_s[256];
  __shared__ __align__(16) float vc_s[256];
  __shared__ __align__(16) float vm_s[256];
  __shared__ __align__(16) float invsum[4];

  const float* X = ws;
  const unsigned short* C1  = (const unsigned short*)((const char*)ws + 1048576);
  const unsigned short* M1  = (const unsigned short*)((const char*)ws + 1572864);
  const unsigned short* C2b = (const unsigned short*)((const char*)ws + 2097152);
  const unsigned short* M2b = (const unsigned short*)((const char*)ws + 2621440);
  const float* SD = (const float*)((const char*)ws + 3670016);

  {
    const int r = (b * NL + p) * ND + tid;
    hp_s[tid] = Hp[r];
    c2_s[tid] = b2f(C2b[r]);
    m2_s[tid] = b2f(M2b[r]);
    vc_s[tid] = vc[tid];
    vm_s[tid] = vm[tid];
    sc4[512 + tid] = SD[(b * NL + p) * NL + tid];
  }
  __syncthreads();

  { // scores c, b, m
    const int qsub = lane >> 4;
    const int hb = c16 * 4;
    for (int qg = 0; qg < 16; ++qg) {
      const int q = wave * 64 + qg * 4 + qsub;
      const unsigned short* c1r = C1 + (b * NL + q) * NH;
      const unsigned short* m1r = M1 + (b * NL + q) * NH;
      const float* xr = X + (b * NL + q) * ND;
      float pc = 0.f, pm = 0.f, pb = 0.f;
      #pragma unroll
      for (int hi = 0; hi < 4; ++hi) {
        const int h = hb + hi * 64;
        s16x4 c1v = *(const s16x4*)(c1r + h);
        s16x4 m1v = *(const s16x4*)(m1r + h);
        f32x4 xv  = *(const f32x4*)(xr + h);
        #pragma unroll
        for (int i = 0; i < 4; ++i) {
          pc += vc_s[h + i] * ftanh(b2f((unsigned short)c1v[i]) + c2_s[h + i]);
          pm += vm_s[h + i] * ftanh(b2f((unsigned short)m1v[i]) - m2_s[h + i]);
          pb += hp_s[h + i] * xv[i];
        }
      }
      #pragma unroll
      for (int m = 1; m < 16; m <<= 1) {
        pc += __shfl_xor(pc, m, 64);
        pm += __shfl_xor(pm, m, 64);
        pb += __shfl_xor(pb, m, 64);
      }
      if (c16 == 0) {
        sc4[q]       = pc;
        sc4[256 + q] = pb;
        sc4[768 + q] = pm;
      }
    }
  }
  __syncthreads();

  { // softmax; wave w owns branch w (0=c,1=b,2=d,3=m)
    float s0 = sc4[wave * 256 + lane];
    float s1 = sc4[wave * 256 + lane + 64];
    float s2 = sc4[wave * 256 + lane + 128];
    float s3 = sc4[wave * 256 + lane + 192];
    float mx = fmaxf(fmaxf(s0, s1), fmaxf(s2, s3));
    #pragma unroll
    for (int m = 1; m < 64; m <<= 1) mx = fmaxf(mx, __shfl_xor(mx, m, 64));
    float e0 = __builtin_amdgcn_exp2f((s0 - mx) * LOG2E);
    float e1 = __builtin_amdgcn_exp2f((s1 - mx) * LOG2E);
    float e2 = __builtin_amdgcn_exp2f((s2 - mx) * LOG2E);
    float e3 = __builtin_amdgcn_exp2f((s3 - mx) * LOG2E);
    float sm = e0 + e1 + e2 + e3;
    #pragma unroll
    for (int m = 1; m < 64; m <<= 1) sm += __shfl_xor(sm, m, 64);
    sc4[wave * 256 + lane]       = e0;
    sc4[wave * 256 + lane + 64]  = e1;
    sc4[wave * 256 + lane + 128] = e2;
    sc4[wave * 256 + lane + 192] = e3;
    if (lane == 0) invsum[wave] = __builtin_amdgcn_rcpf(sm);
  }
  __syncthreads();

  { // attend: wave w covers q in [64w,64w+64) for ALL branches; Hq read once
    const int q0 = wave * 64;
    f32x4 pa0 = {0.f,0.f,0.f,0.f}, pa1 = {0.f,0.f,0.f,0.f};
    f32x4 pa2 = {0.f,0.f,0.f,0.f}, pa3 = {0.f,0.f,0.f,0.f};
    for (int qi = 0; qi < 64; ++qi) {
      const int q = q0 + qi;
      const float ac = sc4[q];
      const float ab = sc4[256 + q];
      const float ad = sc4[512 + q];
      const float am = sc4[768 + q];
      f32x4 hv = *(const f32x4*)(Hq + (b * NL + q) * ND + lane * 4);
      pa0 += ac * hv; pa1 += ab * hv; pa2 += ad * hv; pa3 += am * hv;
    }
    *(f32x4*)(&red[wave][0][lane * 4]) = pa0;
    *(f32x4*)(&red[wave][1][lane * 4]) = pa1;
    *(f32x4*)(&red[wave][2][lane * 4]) = pa2;
    *(f32x4*)(&red[wave][3][lane * 4]) = pa3;
  }
  __syncthreads();

  { // cross-wave reduce + normalize + store; thread owns d=tid for 4 branches
    #pragma unroll
    for (int br = 0; br < 4; ++br) {
      float s = red[0][br][tid] + red[1][br][tid] + red[2][br][tid] + red[3][br][tid];
      out[((br * NB + b) * NL + p) * ND + tid] = s * invsum[br];
    }
  }
}

extern "C" void kernel_launch(void* const* d_in, const int* in_sizes, int n_in,
                              void* d_out, int out_size, void* d_ws, size_t ws_size,
                              hipStream_t stream) {
  const float* Hp  = (const float*)d_in[0];
  const float* Hq  = (const float*)d_in[1];
  const float* Wc1 = (const float*)d_in[2];
  const float* Wc2 = (const float*)d_in[3];
  const float* vc  = (const float*)d_in[4];
  const float* Wb  = (const float*)d_in[5];
  const float* Wd  = (const float*)d_in[6];
  const float* vd  = (const float*)d_in[7];
  const float* Wm  = (const float*)d_in[8];
  const float* vm  = (const float*)d_in[9];
  float* ws = (float*)d_ws;
  float* out = (float*)d_out;

  hipLaunchKernelGGL(prep, dim3(128, 6), dim3(256), 0, stream,
                     Hq, Hp, Wc1, Wc2, Wb, Wm, Wd, ws);
  hipLaunchKernelGGL(dkernel, dim3(256, 4), dim3(256), 0, stream,
                     Hq, Hp, vd, ws);
  hipLaunchKernelGGL(fused2, dim3(256, 4), dim3(256), 0, stream,
                     Hp, Hq, vc, vm, ws, out);
}